// Round 12
// baseline (122.077 us; speedup 1.0000x reference)
//
#include <hip/hip_runtime.h>

#define N_MSG 8192
#define DIM 256
#define KS 5
#define THRESH 0.2f
#define QSCALE 192.0f
#define FILT_I 6672                          // 0.181 * 192^2 (~9-sigma quant margin)
#define N_TEMPORAL (2*(N_MSG-1))             // 16382
#define N_EDGES (N_TEMPORAL + N_MSG*KS)      // 57342
#define ATTR_OFF (2*N_EDGES)                 // 114684
#define VALID_OFF (ATTR_OFF + N_EDGES*64)    // 3784572
#define BM 128
#define NTILE (N_MSG / BM)                   // 64
#define NBLOCKS (NTILE*(NTILE+1)/2)          // 2080
#define CAP 32
#define CS 16                                // ctrl stride (ints), 1 line apart

typedef int i32x4 __attribute__((ext_vector_type(4)));

// Insert (v, j) into descending-sorted top-5 (ties: lower index first).
__device__ __forceinline__ void ins5(float v, int j, float (&vv)[KS], int (&xx)[KS]) {
    float cv = v; int cj = j;
#pragma unroll
    for (int k = 0; k < KS; ++k) {
        bool b = (cv > vv[k]) || (cv == vv[k] && cj < xx[k]);
        float tv = b ? vv[k] : cv; int tj = b ? xx[k] : cj;
        vv[k] = b ? cv : vv[k];    xx[k] = b ? cj : xx[k];
        cv = tv; cj = tj;
    }
}

// wave-level: normalize one row -> embn fp32 + embqT transposed i8; zero cnt
__device__ __forceinline__ void norm_row(int row, int lane,
        const float* __restrict__ emb, float* __restrict__ embn,
        unsigned int* __restrict__ embqT, int* __restrict__ cnt) {
    const float4 x = *(const float4*)(emb + (size_t)row * DIM + lane * 4);
    float ss = x.x * x.x;
    ss = fmaf(x.y, x.y, ss); ss = fmaf(x.z, x.z, ss); ss = fmaf(x.w, x.w, ss);
#pragma unroll
    for (int off = 1; off <= 32; off <<= 1) ss += __shfl_xor(ss, off);
    float nrm = fmaxf(sqrtf(ss), 1e-12f);
    float4 y; y.x = x.x / nrm; y.y = x.y / nrm; y.z = x.z / nrm; y.w = x.w / nrm;
    *(float4*)(embn + (size_t)row * DIM + lane * 4) = y;
    int q0 = (int)rintf(fminf(fmaxf(y.x * QSCALE, -127.f), 127.f));
    int q1 = (int)rintf(fminf(fmaxf(y.y * QSCALE, -127.f), 127.f));
    int q2 = (int)rintf(fminf(fmaxf(y.z * QSCALE, -127.f), 127.f));
    int q3 = (int)rintf(fminf(fmaxf(y.w * QSCALE, -127.f), 127.f));
    unsigned int packed =
        (q0 & 255) | ((q1 & 255) << 8) | ((q2 & 255) << 16) | ((q3 & 255) << 24);
    embqT[(((size_t)(lane >> 2) * N_MSG + row) << 2) | (lane & 3)] = packed;
    if (lane == 0) cnt[row] = 0;
}

// ==== Mega kernel: stripe-claim normalize + temporal outputs + i8 MFMA sim ==
__global__ __launch_bounds__(256, 4)
void mega_k(const float* __restrict__ emb, const float* __restrict__ table,
            float* __restrict__ out, float* __restrict__ embn,
            unsigned int* __restrict__ embqT, int* __restrict__ cnt,
            int* __restrict__ cidx, int* __restrict__ ctrl) {
    int* claim = ctrl;                 // [64] stride CS
    int* ready = ctrl + 64 * CS;       // [64] stride CS
    const int tid = threadIdx.x, lane = tid & 63, wv = tid >> 6;
    __shared__ int sh_claim;

    int t = blockIdx.x;                // triangular decode: bj <= bi
    int bi = (int)((sqrtf(8.0f * (float)t + 1.0f) - 1.0f) * 0.5f);
    while ((bi + 1) * (bi + 2) / 2 <= t) ++bi;
    while (bi * (bi + 1) / 2 > t) --bi;
    int bj = t - bi * (bi + 1) / 2;

    // ---- claim-and-normalize: own bid-stripe (early blocks), then operands --
    int want[3];
    want[0] = (t < NTILE) ? t : -1;    // blocks 0..63 pre-claim stripe=bid
    want[1] = bi;
    want[2] = (bj != bi) ? bj : -1;
#pragma unroll 1
    for (int p = 0; p < 3; ++p) {
        int s = want[p];
        if (s < 0) continue;
        if (p == 1 && s == want[0]) continue;
        if (p == 2 && s == want[0]) continue;
        if (tid == 0) sh_claim = atomicCAS(&claim[s * CS], 0, 1);
        __syncthreads();
        int won = (sh_claim == 0);
        __syncthreads();
        if (!won) continue;
        for (int r = wv; r < BM; r += 4)
            norm_row(s * BM + r, lane, emb, embn, embqT, cnt);
        __threadfence();               // publish stripe (L2 wb to LLC)
        __syncthreads();
        if (tid == 0)
            __hip_atomic_store(&ready[s * CS], 1, __ATOMIC_RELEASE,
                               __HIP_MEMORY_SCOPE_AGENT);
    }

    // ---- temporal outputs (independent; overlaps other blocks' normalize) --
    {
        int s = blockIdx.x * 256 + tid;
        if (s < N_TEMPORAL) {
            int i = s >> 1;
            out[s]             = (s & 1) ? (float)(i + 1) : (float)i;
            out[N_EDGES + s]   = (s & 1) ? (float)i       : (float)(i + 1);
            out[VALID_OFF + s] = 1.0f;
        }
        if (s < N_TEMPORAL * 16) {
            int e = s >> 4, sub = s & 15;
            float4 t4 = *(const float4*)(table + sub * 4);
            *(float4*)(out + ATTR_OFF + (size_t)e * 64 + sub * 4) = t4;
        }
    }

    // ---- wait for operand stripes (relaxed spin; no L2-inv needed: this
    // XCD first touches stripe data only after ready, post-writer-wbl2) ------
    while (__hip_atomic_load(&ready[bi * CS], __ATOMIC_RELAXED,
                             __HIP_MEMORY_SCOPE_AGENT) == 0)
        __builtin_amdgcn_s_sleep(2);
    while (__hip_atomic_load(&ready[bj * CS], __ATOMIC_RELAXED,
                             __HIP_MEMORY_SCOPE_AGENT) == 0)
        __builtin_amdgcn_s_sleep(2);

    // ---- sim: i8 MFMA filter (R8/R11 HW-verified body) ---------------------
    const i32x4* T = (const i32x4*)embqT;
    const int i0 = bi * BM, j0 = bj * BM;
    const int ws = tid >> 6;
    const int wm = ws >> 1, wn = ws & 1;
    const int lr = lane & 15, kb = lane >> 4;

    i32x4 acc[4][4];
#pragma unroll
    for (int m = 0; m < 4; ++m)
#pragma unroll
        for (int n = 0; n < 4; ++n) { i32x4 z = {0, 0, 0, 0}; acc[m][n] = z; }

#pragma unroll
    for (int kc = 0; kc < 4; ++kc) {
        const i32x4* Tc = T + (size_t)(kc * 4 + kb) * N_MSG;
        i32x4 a[4], b[4];
#pragma unroll
        for (int f = 0; f < 4; ++f) {
            a[f] = Tc[i0 + wm * 64 + f * 16 + lr];
            b[f] = Tc[j0 + wn * 64 + f * 16 + lr];
        }
#pragma unroll
        for (int m = 0; m < 4; ++m)
#pragma unroll
            for (int n = 0; n < 4; ++n)
                acc[m][n] = __builtin_amdgcn_mfma_i32_16x16x64_i8(
                    a[m], b[n], acc[m][n], 0, 0, 0);
    }

#pragma unroll
    for (int m = 0; m < 4; ++m) {
        int i = i0 + wm * 64 + m * 16 + kb * 4;
#pragma unroll
        for (int n = 0; n < 4; ++n) {
            int j = j0 + wn * 64 + n * 16 + lr;
#pragma unroll
            for (int r = 0; r < 4; ++r) {
                int v = acc[m][n][r];
                int ii = i + r;
                if (v > FILT_I && j <= ii - 2) {
                    int c = atomicAdd(&cnt[ii], 1);
                    if (c < CAP) cidx[(size_t)ii * CAP + c] = j;
                }
            }
        }
    }
    // cidx published by the implicit device-release at kernel end (R8-proven)
}

// ---- rescue (semantic only): fp32-exact recompute + top-5 + writes --------
__global__ void rescue_sem_k(const float* __restrict__ embn, const int* __restrict__ cnt,
                             const int* __restrict__ cidx, const float* __restrict__ table,
                             float* __restrict__ out) {
    int lane = threadIdx.x & 63;
    int i = blockIdx.x * 4 + (threadIdx.x >> 6);
    int nc = cnt[i]; if (nc > CAP) nc = CAP;

    float fv[KS]; int fx[KS];
#pragma unroll
    for (int k = 0; k < KS; ++k) { fv[k] = -1e30f; fx[k] = -1; }

    if (nc > 0) {
        const float4 a = *(const float4*)(embn + (size_t)i * DIM + lane * 4);
        for (int c = 0; c < nc; ++c) {
            int j = cidx[(size_t)i * CAP + c];
            const float4 b = *(const float4*)(embn + (size_t)j * DIM + lane * 4);
            float p = a.x * b.x;
            p = fmaf(a.y, b.y, p); p = fmaf(a.z, b.z, p); p = fmaf(a.w, b.w, p);
#pragma unroll
            for (int off = 1; off <= 32; off <<= 1) p += __shfl_xor(p, off);
            if (p > THRESH) ins5(p, j, fv, fx);   // identical on all lanes
        }
    }
    int vcnt = 0;
#pragma unroll
    for (int k = 0; k < KS; ++k) vcnt += (fv[k] > THRESH) ? 1 : 0;

    float tsem = table[64 + lane];
#pragma unroll
    for (int k = 0; k < KS; ++k) {
        int e = N_TEMPORAL + i * KS + k;
        bool val = (k < vcnt);
        if (lane == 0) {
            out[e]             = val ? (float)fx[k] : -1.0f;
            out[N_EDGES + e]   = val ? (float)i     : -1.0f;
            out[VALID_OFF + e] = val ? 1.0f : 0.0f;
        }
        out[ATTR_OFF + (size_t)e * 64 + lane] = val ? tsem : 0.0f;
    }
}

// ================= fallback path (no workspace): R8 kernels ================
__global__ void normalize_k(const float* __restrict__ emb, float* __restrict__ embn,
                            unsigned int* __restrict__ embqT, int* __restrict__ cnt) {
    int lane = threadIdx.x & 63;
    int row = blockIdx.x * 4 + (threadIdx.x >> 6);
    norm_row(row, lane, emb, embn, embqT, cnt);
}

__global__ __launch_bounds__(256, 4)
void sim_filter_k(const i32x4* __restrict__ T, int* __restrict__ cnt,
                  int* __restrict__ cidx) {
    int t = blockIdx.x;
    int bi = (int)((sqrtf(8.0f * (float)t + 1.0f) - 1.0f) * 0.5f);
    while ((bi + 1) * (bi + 2) / 2 <= t) ++bi;
    while (bi * (bi + 1) / 2 > t) --bi;
    int bj = t - bi * (bi + 1) / 2;
    const int i0 = bi * BM, j0 = bj * BM;
    const int tid = threadIdx.x;
    const int lane = tid & 63;
    const int ws = tid >> 6;
    const int wm = ws >> 1, wn = ws & 1;
    const int lr = lane & 15, kb = lane >> 4;

    i32x4 acc[4][4];
#pragma unroll
    for (int m = 0; m < 4; ++m)
#pragma unroll
        for (int n = 0; n < 4; ++n) { i32x4 z = {0, 0, 0, 0}; acc[m][n] = z; }
#pragma unroll
    for (int kc = 0; kc < 4; ++kc) {
        const i32x4* Tc = T + (size_t)(kc * 4 + kb) * N_MSG;
        i32x4 a[4], b[4];
#pragma unroll
        for (int f = 0; f < 4; ++f) {
            a[f] = Tc[i0 + wm * 64 + f * 16 + lr];
            b[f] = Tc[j0 + wn * 64 + f * 16 + lr];
        }
#pragma unroll
        for (int m = 0; m < 4; ++m)
#pragma unroll
            for (int n = 0; n < 4; ++n)
                acc[m][n] = __builtin_amdgcn_mfma_i32_16x16x64_i8(a[m], b[n], acc[m][n], 0, 0, 0);
    }
#pragma unroll
    for (int m = 0; m < 4; ++m) {
        int i = i0 + wm * 64 + m * 16 + kb * 4;
#pragma unroll
        for (int n = 0; n < 4; ++n) {
            int j = j0 + wn * 64 + n * 16 + lr;
#pragma unroll
            for (int r = 0; r < 4; ++r) {
                int v = acc[m][n][r];
                int ii = i + r;
                if (v > FILT_I && j <= ii - 2) {
                    int c = atomicAdd(&cnt[ii], 1);
                    if (c < CAP) cidx[(size_t)ii * CAP + c] = j;
                }
            }
        }
    }
}

__global__ void rescue_nf_k(const float* __restrict__ embn, const int* __restrict__ cnt,
                            const int* __restrict__ cidx, float* __restrict__ out) {
    int lane = threadIdx.x & 63;
    int i = blockIdx.x * 4 + (threadIdx.x >> 6);
    int nc = cnt[i]; if (nc > CAP) nc = CAP;
    float fv[KS]; int fx[KS];
#pragma unroll
    for (int k = 0; k < KS; ++k) { fv[k] = -1e30f; fx[k] = -1; }
    if (nc > 0) {
        const float4 a = *(const float4*)(embn + (size_t)i * DIM + lane * 4);
        for (int c = 0; c < nc; ++c) {
            int j = cidx[(size_t)i * CAP + c];
            const float4 b = *(const float4*)(embn + (size_t)j * DIM + lane * 4);
            float p = a.x * b.x;
            p = fmaf(a.y, b.y, p); p = fmaf(a.z, b.z, p); p = fmaf(a.w, b.w, p);
#pragma unroll
            for (int off = 1; off <= 32; off <<= 1) p += __shfl_xor(p, off);
            if (p > THRESH) ins5(p, j, fv, fx);
        }
    }
    int vcnt = 0;
#pragma unroll
    for (int k = 0; k < KS; ++k) vcnt += (fv[k] > THRESH) ? 1 : 0;
    if (lane < KS) {
        int e = N_TEMPORAL + i * KS + lane;
        bool val = (lane < vcnt);
        out[e]             = val ? (float)fx[lane] : -1.0f;
        out[N_EDGES + e]   = val ? (float)i        : -1.0f;
        out[VALID_OFF + e] = val ? 1.0f : 0.0f;
    }
}

__global__ void attr_out_k(const float* __restrict__ table, float* __restrict__ out) {
    int idx = blockIdx.x * 256 + threadIdx.x;
    int e = idx >> 4, sub = idx & 15;
    if (e >= N_EDGES) return;
    float4 a4;
    if (e < N_TEMPORAL) {
        a4 = *(const float4*)(table + sub * 4);
        if (sub == 0) {
            int i = e >> 1;
            out[e]             = (e & 1) ? (float)(i + 1) : (float)i;
            out[N_EDGES + e]   = (e & 1) ? (float)i       : (float)(i + 1);
            out[VALID_OFF + e] = 1.0f;
        }
    } else {
        float vld = out[VALID_OFF + e];
        a4 = *(const float4*)(table + 64 + sub * 4);
        a4.x *= vld; a4.y *= vld; a4.z *= vld; a4.w *= vld;
    }
    *(float4*)(out + ATTR_OFF + (size_t)e * 64 + sub * 4) = a4;
}

extern "C" void kernel_launch(void* const* d_in, const int* in_sizes, int n_in,
                              void* d_out, int out_size, void* d_ws, size_t ws_size,
                              hipStream_t stream) {
    const float* emb   = (const float*)d_in[0];
    const float* table = (const float*)d_in[1];
    float* out = (float*)d_out;

    size_t embn_f  = (size_t)N_MSG * DIM;              // 2,097,152 floats
    size_t embq_f  = (size_t)N_MSG * DIM / 4;          // 524,288 words
    size_t cidx_f  = (size_t)N_MSG * CAP;              // 262,144
    size_t cnt_f   = N_MSG;                            // 8,192
    size_t ctrl_f  = 128 * CS;                         // claim+ready, 2048 ints
    size_t need_bytes = (embn_f + embq_f + cidx_f + cnt_f + ctrl_f) * 4;  // ~11.5 MB

    bool have_ws = (ws_size >= need_bytes);
    float* scratch = have_ws ? (float*)d_ws
                             : out + ATTR_OFF;  // carve attr region; attr written last
    float*        embn  = scratch;
    unsigned int* embqT = (unsigned int*)(scratch + embn_f);
    int*          cidx  = (int*)(scratch + embn_f + embq_f);
    int*          cnt   = (int*)(scratch + embn_f + embq_f + cidx_f);
    int*          ctrl  = (int*)(scratch + embn_f + embq_f + cidx_f + cnt_f);

    if (have_ws) {
        hipMemsetAsync(ctrl, 0, ctrl_f * 4, stream);
        mega_k<<<NBLOCKS, 256, 0, stream>>>(emb, table, out, embn, embqT, cnt, cidx, ctrl);
        rescue_sem_k<<<N_MSG / 4, 256, 0, stream>>>(embn, cnt, cidx, table, out);
    } else {
        normalize_k<<<N_MSG / 4, 256, 0, stream>>>(emb, embn, embqT, cnt);
        sim_filter_k<<<NBLOCKS, 256, 0, stream>>>((const i32x4*)embqT, cnt, cidx);
        rescue_nf_k<<<N_MSG / 4, 256, 0, stream>>>(embn, cnt, cidx, out);
        attr_out_k<<<((size_t)N_EDGES * 16 + 255) / 256, 256, 0, stream>>>(table, out);
    }
}

// Round 14
// 63.403 us; speedup vs baseline: 1.9254x; 1.9254x over previous
//
#include <hip/hip_runtime.h>

#define N_MSG 8192
#define DIM 256
#define KS 5
#define THRESH 0.2f
#define QSCALE 192.0f
#define FILT_I 6672                          // 0.181 * 192^2 (~9-sigma quant margin)
#define N_TEMPORAL (2*(N_MSG-1))             // 16382
#define N_EDGES (N_TEMPORAL + N_MSG*KS)      // 57342
#define ATTR_OFF (2*N_EDGES)                 // 114684
#define VALID_OFF (ATTR_OFF + N_EDGES*64)    // 3784572
#define BM 128
#define NTILE (N_MSG / BM)                   // 64
#define NBLOCKS (NTILE*(NTILE+1)/2)          // 2080
#define CAP 32

typedef int   i32x4 __attribute__((ext_vector_type(4)));
typedef float f32x4 __attribute__((ext_vector_type(4)));

// Insert (v, j) into descending-sorted top-5 (ties: lower index first).
__device__ __forceinline__ void ins5(float v, int j, float (&vv)[KS], int (&xx)[KS]) {
    float cv = v; int cj = j;
#pragma unroll
    for (int k = 0; k < KS; ++k) {
        bool b = (cv > vv[k]) || (cv == vv[k] && cj < xx[k]);
        float tv = b ? vv[k] : cv; int tj = b ? xx[k] : cj;
        vv[k] = b ? cv : vv[k];    xx[k] = b ? cj : xx[k];
        cv = tv; cj = tj;
    }
}

// ---- Kernel A: L2-normalize rows -> fp32 copy + TRANSPOSED int8 quant -----
// embqT chunk layout (16 B = 16 i8): chunk_id = c16 * N_MSG + row (c16 = k/16)
// = mfma_i32_16x16x64_i8 fragment order (HW-verified R7/R8).
// NON-TEMPORAL (no-allocate) stores: keep cross-kernel operands out of the
// writer XCD's L2 (no dirty lines) so sim/rescue first-touch pulls clean
// LLC lines instead of paying cross-XCD writeback+refetch.
__global__ void normalize_k(const float* __restrict__ emb, float* __restrict__ embn,
                            unsigned int* __restrict__ embqT, int* __restrict__ cnt) {
    int lane = threadIdx.x & 63;
    int row = blockIdx.x * 4 + (threadIdx.x >> 6);
    const float4 x = *(const float4*)(emb + (size_t)row * DIM + lane * 4);
    float ss = x.x * x.x;
    ss = fmaf(x.y, x.y, ss); ss = fmaf(x.z, x.z, ss); ss = fmaf(x.w, x.w, ss);
#pragma unroll
    for (int off = 1; off <= 32; off <<= 1) ss += __shfl_xor(ss, off);
    float nrm = fmaxf(sqrtf(ss), 1e-12f);
    f32x4 y; y.x = x.x / nrm; y.y = x.y / nrm; y.z = x.z / nrm; y.w = x.w / nrm;
    __builtin_nontemporal_store(y, (f32x4*)(embn + (size_t)row * DIM + lane * 4));
    int q0 = (int)rintf(fminf(fmaxf(y.x * QSCALE, -127.f), 127.f));
    int q1 = (int)rintf(fminf(fmaxf(y.y * QSCALE, -127.f), 127.f));
    int q2 = (int)rintf(fminf(fmaxf(y.z * QSCALE, -127.f), 127.f));
    int q3 = (int)rintf(fminf(fmaxf(y.w * QSCALE, -127.f), 127.f));
    unsigned int packed =
        (q0 & 255) | ((q1 & 255) << 8) | ((q2 & 255) << 16) | ((q3 & 255) << 24);
    __builtin_nontemporal_store(packed,
        &embqT[(((size_t)(lane >> 2) * N_MSG + row) << 2) | (lane & 3)]);
    if (lane == 0) cnt[row] = 0;
}

// ---- Kernel B: i8 MFMA sim filter — no LDS, direct coalesced frag loads ---
// (byte-identical to the R8 62.8-us version)
__global__ __launch_bounds__(256, 4)
void sim_filter_k(const i32x4* __restrict__ T, int* __restrict__ cnt,
                  int* __restrict__ cidx) {
    int t = blockIdx.x;                       // triangular decode: bj <= bi
    int bi = (int)((sqrtf(8.0f * (float)t + 1.0f) - 1.0f) * 0.5f);
    while ((bi + 1) * (bi + 2) / 2 <= t) ++bi;
    while (bi * (bi + 1) / 2 > t) --bi;
    int bj = t - bi * (bi + 1) / 2;
    const int i0 = bi * BM, j0 = bj * BM;

    const int tid = threadIdx.x;
    const int lane = tid & 63;
    const int ws = tid >> 6;                  // wave id 0..3
    const int wm = ws >> 1, wn = ws & 1;      // 2x2 wave grid, 64x64 each
    const int lr = lane & 15, kb = lane >> 4;

    i32x4 acc[4][4];
#pragma unroll
    for (int m = 0; m < 4; ++m)
#pragma unroll
        for (int n = 0; n < 4; ++n) { i32x4 z = {0, 0, 0, 0}; acc[m][n] = z; }

#pragma unroll
    for (int kc = 0; kc < 4; ++kc) {
        const i32x4* Tc = T + (size_t)(kc * 4 + kb) * N_MSG;
        i32x4 a[4], b[4];
#pragma unroll
        for (int f = 0; f < 4; ++f) {
            a[f] = Tc[i0 + wm * 64 + f * 16 + lr];
            b[f] = Tc[j0 + wn * 64 + f * 16 + lr];
        }
#pragma unroll
        for (int m = 0; m < 4; ++m)
#pragma unroll
            for (int n = 0; n < 4; ++n)
                acc[m][n] = __builtin_amdgcn_mfma_i32_16x16x64_i8(a[m], b[n], acc[m][n], 0, 0, 0);
    }

    // epilogue: rare filtered atomic append (indices only; fp32 rescue later)
#pragma unroll
    for (int m = 0; m < 4; ++m) {
        int i = i0 + wm * 64 + m * 16 + kb * 4;
#pragma unroll
        for (int n = 0; n < 4; ++n) {
            int j = j0 + wn * 64 + n * 16 + lr;
#pragma unroll
            for (int r = 0; r < 4; ++r) {
                int v = acc[m][n][r];
                int ii = i + r;
                if (v > FILT_I && j <= ii - 2) {
                    int c = atomicAdd(&cnt[ii], 1);
                    if (c < CAP) cidx[(size_t)ii * CAP + c] = j;
                }
            }
        }
    }
}

// ---- Kernel C: fp32-exact rescue + (optionally fused) output writes -------
template<bool FUSE>
__global__ void rescue_k(const float* __restrict__ embn, const int* __restrict__ cnt,
                         const int* __restrict__ cidx, const float* __restrict__ table,
                         float* __restrict__ out) {
    int lane = threadIdx.x & 63;
    int i = blockIdx.x * 4 + (threadIdx.x >> 6);
    int nc = cnt[i]; if (nc > CAP) nc = CAP;

    float fv[KS]; int fx[KS];
#pragma unroll
    for (int k = 0; k < KS; ++k) { fv[k] = -1e30f; fx[k] = -1; }

    if (nc > 0) {
        const float4 a = *(const float4*)(embn + (size_t)i * DIM + lane * 4);
        for (int c = 0; c < nc; ++c) {
            int j = cidx[(size_t)i * CAP + c];
            const float4 b = *(const float4*)(embn + (size_t)j * DIM + lane * 4);
            float p = a.x * b.x;
            p = fmaf(a.y, b.y, p); p = fmaf(a.z, b.z, p); p = fmaf(a.w, b.w, p);
#pragma unroll
            for (int off = 1; off <= 32; off <<= 1) p += __shfl_xor(p, off);
            if (p > THRESH) ins5(p, j, fv, fx);   // identical on all lanes
        }
    }
    int vcnt = 0;
#pragma unroll
    for (int k = 0; k < KS; ++k) vcnt += (fv[k] > THRESH) ? 1 : 0;

    float tsem = FUSE ? table[64 + lane] : 0.0f;
#pragma unroll
    for (int k = 0; k < KS; ++k) {
        int e = N_TEMPORAL + i * KS + k;
        bool val = (k < vcnt);
        if (lane == 0) {
            out[e]             = val ? (float)fx[k] : -1.0f;
            out[N_EDGES + e]   = val ? (float)i     : -1.0f;
            out[VALID_OFF + e] = val ? 1.0f : 0.0f;
        }
        if (FUSE) out[ATTR_OFF + (size_t)e * 64 + lane] = val ? tsem : 0.0f;
    }
    if (FUSE) {
        if (i < N_MSG - 1) {
            float ttem = table[lane];
            int e0 = 2 * i;
            out[ATTR_OFF + (size_t)e0 * 64 + lane]       = ttem;
            out[ATTR_OFF + (size_t)(e0 + 1) * 64 + lane] = ttem;
            if (lane == 0) {
                out[e0]                 = (float)i;
                out[N_EDGES + e0]       = (float)(i + 1);
                out[VALID_OFF + e0]     = 1.0f;
                out[e0 + 1]             = (float)(i + 1);
                out[N_EDGES + e0 + 1]   = (float)i;
                out[VALID_OFF + e0 + 1] = 1.0f;
            }
        }
    }
}

// ---- Kernel D (fallback only, when scratch carved from attr region) -------
__global__ void attr_out_k(const float* __restrict__ table, float* __restrict__ out) {
    int idx = blockIdx.x * 256 + threadIdx.x;
    int e = idx >> 4, sub = idx & 15;
    if (e >= N_EDGES) return;
    float4 a4;
    if (e < N_TEMPORAL) {
        a4 = *(const float4*)(table + sub * 4);
        if (sub == 0) {
            int i = e >> 1;
            out[e]             = (e & 1) ? (float)(i + 1) : (float)i;
            out[N_EDGES + e]   = (e & 1) ? (float)i       : (float)(i + 1);
            out[VALID_OFF + e] = 1.0f;
        }
    } else {
        float vld = out[VALID_OFF + e];
        a4 = *(const float4*)(table + 64 + sub * 4);
        a4.x *= vld; a4.y *= vld; a4.z *= vld; a4.w *= vld;
    }
    *(float4*)(out + ATTR_OFF + (size_t)e * 64 + sub * 4) = a4;
}

extern "C" void kernel_launch(void* const* d_in, const int* in_sizes, int n_in,
                              void* d_out, int out_size, void* d_ws, size_t ws_size,
                              hipStream_t stream) {
    const float* emb   = (const float*)d_in[0];
    const float* table = (const float*)d_in[1];
    float* out = (float*)d_out;

    size_t embn_f  = (size_t)N_MSG * DIM;              // 2,097,152 floats
    size_t embq_f  = (size_t)N_MSG * DIM / 4;          // 524,288 words
    size_t cidx_f  = (size_t)N_MSG * CAP;              // 262,144
    size_t cnt_f   = N_MSG;                            // 8,192
    size_t need_bytes = (embn_f + embq_f + cidx_f + cnt_f) * 4;  // ~11.5 MB

    bool have_ws = (ws_size >= need_bytes);
    float* scratch = have_ws ? (float*)d_ws
                             : out + ATTR_OFF;  // carve attr region; attr written last
    float*        embn  = scratch;
    unsigned int* embqT = (unsigned int*)(scratch + embn_f);
    int*          cidx  = (int*)(scratch + embn_f + embq_f);
    int*          cnt   = (int*)(scratch + embn_f + embq_f + cidx_f);

    normalize_k<<<N_MSG / 4, 256, 0, stream>>>(emb, embn, embqT, cnt);
    sim_filter_k<<<NBLOCKS, 256, 0, stream>>>((const i32x4*)embqT, cnt, cidx);
    if (have_ws) {
        rescue_k<true><<<N_MSG / 4, 256, 0, stream>>>(embn, cnt, cidx, table, out);
    } else {
        rescue_k<false><<<N_MSG / 4, 256, 0, stream>>>(embn, cnt, cidx, table, out);
        attr_out_k<<<((size_t)N_EDGES * 16 + 255) / 256, 256, 0, stream>>>(table, out);
    }
}